// Round 3
// baseline (33.116 us; speedup 1.0000x reference)
//
#include <hip/hip_runtime.h>

constexpr int    NN     = 8192;
constexpr float  MARGIN = 0.01f;
constexpr int    TI     = 256;           // i-rows per block == threads
constexpr int    TJ     = 128;           // j-chunk per block
constexpr int    NTI    = NN / TI;       // 32
constexpr int    NTJ    = NN / TJ;       // 64
constexpr int    NBLOCKS = NTJ * NTI - NTI * (NTI - 1); // 1056
constexpr int    PREP_BLOCKS = NN / 256; // 32

// d_ws layout (bytes):
//   [0]      unsigned int counter          (reset by prep each call)
//   [256]    double price_part[32]
//   [512]    double rank_part[1056]
//   [16384]  float2 r2[8192]               (pred_r, act_r)
static __device__ __forceinline__ unsigned int* ws_counter(void* w) { return (unsigned int*)w; }

__global__ __launch_bounds__(256)
void prep_kernel(const float* __restrict__ pred,
                 const float* __restrict__ act,
                 const float* __restrict__ prev,
                 float2* __restrict__ r2,
                 double* __restrict__ price_part,
                 unsigned int* __restrict__ counter)
{
    const int g  = blockIdx.x * 256 + threadIdx.x;
    const float pv = prev[g];
    const float p  = pred[g];
    const float a  = act[g];
    r2[g] = make_float2((p - pv) / pv, (a - pv) / pv);

    const float d  = p - a;
    double pp = (double)(d * d);
    for (int off = 32; off > 0; off >>= 1) pp += __shfl_down(pp, off, 64);
    __shared__ double red[4];
    if ((threadIdx.x & 63) == 0) red[threadIdx.x >> 6] = pp;
    __syncthreads();
    if (threadIdx.x == 0) {
        price_part[blockIdx.x] = red[0] + red[1] + red[2] + red[3];
        if (blockIdx.x == 0) *counter = 0u;   // stream order: done before pair_kernel starts
    }
}

// Sum of hinge over ALL ordered pairs (i,j) including i==j.
// Diagonal contributes exactly MARGIN per element (ad=0 -> s=-1, pd=0);
// subtracted analytically. count = NN*(NN-1) (continuous data: no off-diag ties;
// any tie would perturb the result ~1e-7, far below the 2.6e-2 threshold).
__global__ __launch_bounds__(256)
void pair_kernel(const float2* __restrict__ r2,
                 double* __restrict__ rank_part,
                 const double* __restrict__ price_part,
                 unsigned int* __restrict__ counter,
                 float* __restrict__ out)
{
    // decode flat block id -> (ib, jc); row ib has (NTJ - 2*ib) j-chunks
    int t  = blockIdx.x;
    int ib = 0;
    while (t >= NTJ - 2 * ib) { t -= NTJ - 2 * ib; ++ib; }
    const int  jc  = 2 * ib + t;
    const bool dbl = (t >= 2);             // strictly off-diagonal tile -> double

    const int tid = threadIdx.x;
    const int i   = ib * TI + tid;
    const float2 ri  = r2[i];
    const float  pri = ri.x;
    const float  ari = ri.y;

    // wave-uniform j-stream -> scalar loads (SMEM), zero LDS in the loop
    const float2* __restrict__ rj = r2 + jc * TJ;

    float a0 = 0.f, a1 = 0.f, a2 = 0.f, a3 = 0.f;

#define PAIR(tv, acc)                                      \
    {                                                      \
        const float ad = ari - (tv).y;                     \
        const float pd = pri - (tv).x;                     \
        const float u  = (ad > 0.0f) ? -pd : pd;           \
        acc += fmaxf(0.0f, MARGIN + u);                    \
    }

#pragma unroll
    for (int j = 0; j < TJ; j += 4) {
        const float2 t0 = rj[j + 0];
        const float2 t1 = rj[j + 1];
        const float2 t2 = rj[j + 2];
        const float2 t3 = rj[j + 3];
        PAIR(t0, a0);
        PAIR(t1, a1);
        PAIR(t2, a2);
        PAIR(t3, a3);
    }
#undef PAIR

    double ws = (double)((a0 + a1) + (a2 + a3));
    if (dbl) ws += ws;

    for (int off = 32; off > 0; off >>= 1) ws += __shfl_down(ws, off, 64);

    __shared__ double red[4];
    __shared__ bool   lastf;
    if ((tid & 63) == 0) red[tid >> 6] = ws;
    __syncthreads();
    if (tid == 0) {
        rank_part[blockIdx.x] = red[0] + red[1] + red[2] + red[3];
        const unsigned tk = __hip_atomic_fetch_add(counter, 1u, __ATOMIC_ACQ_REL,
                                                   __HIP_MEMORY_SCOPE_AGENT);
        lastf = (tk == (unsigned)(NBLOCKS - 1));
    }
    __syncthreads();
    if (!lastf) return;

    // last block: final reduction (acquire on counter ordered prior writes)
    double s = 0.0, p = 0.0;
    for (int k = tid; k < NBLOCKS; k += 256) s += rank_part[k];
    for (int k = tid; k < PREP_BLOCKS; k += 256) p += price_part[k];
    for (int off = 32; off > 0; off >>= 1) {
        s += __shfl_down(s, off, 64);
        p += __shfl_down(p, off, 64);
    }
    __shared__ double rs2[4], rp2[4];
    if ((tid & 63) == 0) { rs2[tid >> 6] = s; rp2[tid >> 6] = p; }
    __syncthreads();
    if (tid == 0) {
        const double S = rs2[0] + rs2[1] + rs2[2] + rs2[3];
        const double P = rp2[0] + rp2[1] + rp2[2] + rp2[3];
        const double rank = (S - (double)NN * (double)MARGIN)
                          / ((double)NN * (double)(NN - 1));
        out[0] = (float)(0.5 * (P / (double)NN) + 0.5 * rank);
    }
}

extern "C" void kernel_launch(void* const* d_in, const int* in_sizes, int n_in,
                              void* d_out, int out_size, void* d_ws, size_t ws_size,
                              hipStream_t stream)
{
    const float* pred = (const float*)d_in[0];
    const float* act  = (const float*)d_in[1];
    const float* prev = (const float*)d_in[2];

    char* w = (char*)d_ws;
    unsigned int* counter    = (unsigned int*)(w + 0);
    double*       price_part = (double*)(w + 256);
    double*       rank_part  = (double*)(w + 512);
    float2*       r2         = (float2*)(w + 16384);

    prep_kernel<<<PREP_BLOCKS, 256, 0, stream>>>(pred, act, prev, r2, price_part, counter);
    pair_kernel<<<NBLOCKS, 256, 0, stream>>>(r2, rank_part, price_part, counter, (float*)d_out);
}